// Round 4
// baseline (435.376 us; speedup 1.0000x reference)
//
#include <hip/hip_runtime.h>
#include <math.h>
#include <stdint.h>

#define EPS     1e-7f
#define NR      8192
#define DX      256
#define DZ      64
#define KNN     5
#define KEEP    8               // per-split kept candidates (packed u32)
#define NPOOL   (NSPLIT * KEEP) // 64 = one per lane in finalize
#define NCAND   16              // exact-recompute pool in finalize
#define NSPLIT  8
#define JS      (NR / NSPLIT)   // 1024
#define JT      64              // j-cols staged per chunk
#define NCHUNK  (JS / JT)       // 16
#define RBLK    64              // i-rows per block

typedef _Float16 f16x8 __attribute__((ext_vector_type(8)));
typedef _Float16 f16x4 __attribute__((ext_vector_type(4)));
typedef float    f32x4 __attribute__((ext_vector_type(4)));

__device__ __forceinline__ uint32_t umin_(uint32_t a, uint32_t b) { return a < b ? a : b; }
__device__ __forceinline__ uint32_t umax_(uint32_t a, uint32_t b) { return a < b ? b : a; }

// ------------------------------------------------- X -> f16 + row sq-sums (+ zero out)
__global__ __launch_bounds__(256) void split_k(const float* __restrict__ X,
                                               _Float16* __restrict__ Xh,
                                               float* __restrict__ sqX,
                                               float* __restrict__ out) {
    if (blockIdx.x == 0 && threadIdx.x == 0) out[0] = 0.0f;  // finalize runs later on stream
    const int row  = blockIdx.x * 4 + (threadIdx.x >> 6);
    const int lane = threadIdx.x & 63;
    const float4 v = *(const float4*)&X[(size_t)row * DX + lane * 4];
    float s = v.x * v.x + v.y * v.y + v.z * v.z + v.w * v.w;
    f16x4 h;
    h[0] = (_Float16)v.x; h[1] = (_Float16)v.y;
    h[2] = (_Float16)v.z; h[3] = (_Float16)v.w;
    *(f16x4*)&Xh[(size_t)row * DX + lane * 4] = h;
    #pragma unroll
    for (int o = 32; o > 0; o >>= 1) s += __shfl_down(s, o);
    if (lane == 0) sqX[row] = s;
}

// ------------------------------------------------- f16 MFMA GEMM + fused packed top-5
// 4 waves/block, 4 blocks/CU. Wave w: rows half h=w>>1 (32 rows, A in regs), j-half sp=w&1.
// B staged via global_load_lds (16B) with source-side XOR swizzle. Candidates packed
// (d2_bits & ~0x1FFF)|j -> u32 min chains; exact fp32 re-rank in finalize fixes quantization.
__global__ __launch_bounds__(256, 4) void mfma_topk_k(const _Float16* __restrict__ Xh,
                                                      const float* __restrict__ sqX,
                                                      uint32_t* __restrict__ partials) {
    __shared__ __align__(16) uint8_t smem[32768];      // B staging: 2048 slots x 16 B
    __shared__ uint32_t mb2[RBLK][2][KNN];             // cross-wave merge (2.5 KB)
    f16x8* BhV = (f16x8*)smem;

    const int tid  = threadIdx.x;
    const int w    = tid >> 6;
    const int lane = tid & 63;
    const int n    = lane & 15;
    const int quad = lane >> 4;
    const int x7   = n & 7;
    const int h    = w >> 1;
    const int sp   = w & 1;
    const int ib   = blockIdx.x * RBLK;
    const int jb0  = blockIdx.y * JS;
    const int rowbase = ib + h * 32;

    // A fragments: 2 rowgroups x 8 k-steps (A layout: row=lane&15, k=quad*8+j)
    f16x8 Ah[2][8];
    #pragma unroll
    for (int g = 0; g < 2; ++g)
        #pragma unroll
        for (int ks = 0; ks < 8; ++ks)
            Ah[g][ks] = *(const f16x8*)(Xh + (size_t)(rowbase + g * 16 + n) * DX + ks * 32 + quad * 8);

    float sqi[2][4];
    #pragma unroll
    for (int g = 0; g < 2; ++g) {
        const float4 t = *(const float4*)&sqX[rowbase + g * 16 + quad * 4];
        sqi[g][0] = t.x; sqi[g][1] = t.y; sqi[g][2] = t.z; sqi[g][3] = t.w;
    }

    uint32_t best[8][KNN];   // q = g*4+r; ascending
    #pragma unroll
    for (int q = 0; q < 8; ++q)
        #pragma unroll
        for (int k = 0; k < KNN; ++k) best[q][k] = 0xFFFFFFFFu;

    // staging source map: slot q = w*512 + u*64 + lane holds row sj=q>>5, chunk c=(q&31)^(sj&7)
    int srcoff[8];
    #pragma unroll
    for (int u = 0; u < 8; ++u) {
        const int q  = w * 512 + u * 64 + lane;
        const int sj = q >> 5;
        const int c  = (q & 31) ^ (sj & 7);
        srcoff[u] = sj * DX + c * 8;
    }

    for (int jc = 0; jc < NCHUNK; ++jc) {
        const int jb = jb0 + jc * JT;
        __syncthreads();  // previous chunk's readers done
        #pragma unroll
        for (int u = 0; u < 8; ++u) {
            const _Float16* src = Xh + (size_t)jb * DX + srcoff[u];
            uint8_t* dst = smem + (size_t)(w * 512 + u * 64) * 16;  // wave-uniform; HW adds lane*16
            __builtin_amdgcn_global_load_lds((const __attribute__((address_space(1))) uint32_t*)src,
                                             (__attribute__((address_space(3))) uint32_t*)dst,
                                             16, 0, 0);
        }
        __syncthreads();  // drains vmcnt -> staging visible

        f32x4 acc[2][2];  // [si][g]
        #pragma unroll
        for (int si = 0; si < 2; ++si)
            #pragma unroll
            for (int g = 0; g < 2; ++g)
                #pragma unroll
                for (int r = 0; r < 4; ++r) acc[si][g][r] = 0.0f;

        #pragma unroll
        for (int ks = 0; ks < 8; ++ks) {
            #pragma unroll
            for (int si = 0; si < 2; ++si) {
                const int s   = sp * 2 + si;
                const int idx = (s * 16 + n) * 32 + ((ks * 4 + quad) ^ x7);
                const f16x8 b = BhV[idx];
                acc[si][0] = __builtin_amdgcn_mfma_f32_16x16x32_f16(Ah[0][ks], b, acc[si][0], 0, 0, 0);
                acc[si][1] = __builtin_amdgcn_mfma_f32_16x16x32_f16(Ah[1][ks], b, acc[si][1], 0, 0, 0);
            }
        }

        // fold 16 candidates/lane (C layout: col=n, row=quad*4+reg)
        #pragma unroll
        for (int si = 0; si < 2; ++si) {
            const int j = jb + (sp * 2 + si) * 16 + n;
            const float sqj = sqX[j];
            #pragma unroll
            for (int g = 0; g < 2; ++g) {
                #pragma unroll
                for (int r = 0; r < 4; ++r) {
                    const int i = rowbase + g * 16 + quad * 4 + r;
                    if (j == i) continue;  // reference drops the diagonal
                    const float d2 = (sqi[g][r] + sqj) - 2.0f * acc[si][g][r];
                    const uint32_t cand = (__float_as_uint(d2) & 0xFFFFE000u) | (uint32_t)j;
                    const int q = g * 4 + r;
                    if (cand < best[q][KNN - 1]) {
                        uint32_t ck = cand;
                        #pragma unroll
                        for (int k = 0; k < KNN; ++k) {
                            const uint32_t bk = best[q][k];
                            best[q][k] = umin_(ck, bk); ck = umax_(ck, bk);
                        }
                    }
                }
            }
        }
    }

    // wave-internal merge across the 16 n-lanes (rows live in a fixed quad-group):
    // sorted-merge identity c_k = min(b_k, max(a_0,b_{k-1}), ..., max(a_{k-1},b_0), a_k)
    #pragma unroll
    for (int mask = 1; mask <= 8; mask <<= 1) {
        #pragma unroll
        for (int q = 0; q < 8; ++q) {
            uint32_t a0 = best[q][0], a1 = best[q][1], a2 = best[q][2], a3 = best[q][3], a4 = best[q][4];
            const uint32_t b0 = __shfl_xor(a0, mask);
            const uint32_t b1 = __shfl_xor(a1, mask);
            const uint32_t b2 = __shfl_xor(a2, mask);
            const uint32_t b3 = __shfl_xor(a3, mask);
            const uint32_t b4 = __shfl_xor(a4, mask);
            best[q][0] = umin_(a0, b0);
            best[q][1] = umin_(umin_(a1, b1), umax_(a0, b0));
            best[q][2] = umin_(umin_(a2, b2), umin_(umax_(a0, b1), umax_(a1, b0)));
            best[q][3] = umin_(umin_(a3, b3),
                               umin_(umax_(a1, b1), umin_(umax_(a0, b2), umax_(a2, b0))));
            best[q][4] = umin_(umin_(a4, b4),
                               umin_(umin_(umax_(a0, b3), umax_(a1, b2)),
                                     umin_(umax_(a2, b1), umax_(a3, b0))));
        }
    }

    // cross-wave (sp) merge via tiny padded LDS; emit KEEP=8 per row per split
    if (n < KNN) {
        #pragma unroll
        for (int q = 0; q < 8; ++q) {
            const int rloc = h * 32 + (q >> 2) * 16 + quad * 4 + (q & 3);
            mb2[rloc][sp][n] = best[q][n];
        }
    }
    __syncthreads();
    if (tid < RBLK) {
        uint32_t a0 = mb2[tid][0][0], a1 = mb2[tid][0][1], a2 = mb2[tid][0][2],
                 a3 = mb2[tid][0][3], a4 = mb2[tid][0][4];
        uint32_t b0 = mb2[tid][1][0], b1 = mb2[tid][1][1], b2 = mb2[tid][1][2],
                 b3 = mb2[tid][1][3], b4 = mb2[tid][1][4];
        uint32_t o[KEEP];
        o[0] = umin_(a0, b0);
        o[1] = umin_(umin_(a1, b1), umax_(a0, b0));
        o[2] = umin_(umin_(a2, b2), umin_(umax_(a0, b1), umax_(a1, b0)));
        o[3] = umin_(umin_(a3, b3), umin_(umax_(a1, b1), umin_(umax_(a0, b2), umax_(a2, b0))));
        o[4] = umin_(umin_(a4, b4), umin_(umin_(umax_(a0, b3), umax_(a1, b2)),
                                          umin_(umax_(a2, b1), umax_(a3, b0))));
        o[5] = umin_(umin_(umax_(a0, b4), umax_(a4, b0)),
                     umin_(umax_(a1, b3), umin_(umax_(a2, b2), umax_(a3, b1))));
        o[6] = umin_(umin_(umax_(a1, b4), umax_(a4, b1)),
                     umin_(umax_(a2, b3), umax_(a3, b2)));
        o[7] = umin_(umax_(a2, b4), umin_(umax_(a3, b3), umax_(a4, b2)));
        #pragma unroll
        for (int k = 0; k < KEEP; ++k)
            partials[(size_t)(ib + tid) * NPOOL + blockIdx.y * KEEP + k] = o[k];
    }
}

// ------------------------------------------------- one wave per row: approx-rank prefilter
// (64-pool = 1/lane), exact fp32 re-rank (16 cand x 4 lanes), lid, loss
__global__ __launch_bounds__(1024) void finalize_k(const uint32_t* __restrict__ parts,
                                                   const float* __restrict__ X,
                                                   const float* __restrict__ Z,
                                                   const float* __restrict__ sqX,
                                                   float* __restrict__ out) {
    __shared__ uint32_t jl[16][NCAND];
    __shared__ float wsum[16];
    const int wv   = threadIdx.x >> 6;
    const int lane = threadIdx.x & 63;
    const int i    = blockIdx.x * 16 + wv;

    // rank the 64 packed candidates (splits disjoint -> keys distinct)
    const uint32_t packed = parts[(size_t)i * NPOOL + lane];
    int rank = 0;
    #pragma unroll
    for (int m = 0; m < 64; ++m) {
        const uint32_t v = __shfl(packed, m);
        rank += (v < packed) || (v == packed && m < lane);
    }
    if (rank < NCAND) jl[wv][rank] = packed & 0x1FFFu;
    __syncthreads();

    // exact fp32 d2: candidate c = lane>>2, quarter = lane&3 (64-dim slice each)
    const int c = lane >> 2, qtr = lane & 3;
    const int jc = (int)jl[wv][c];
    {
    }
    const float4* xi = (const float4*)(X + (size_t)i * DX) + qtr * 16;
    const float4* xj = (const float4*)(X + (size_t)jc * DX) + qtr * 16;
    float a0 = 0.f, a1 = 0.f, a2 = 0.f, a3 = 0.f;
    #pragma unroll
    for (int t = 0; t < 16; t += 4) {
        const float4 u0 = xi[t],     v0 = xj[t];
        const float4 u1 = xi[t + 1], v1 = xj[t + 1];
        const float4 u2 = xi[t + 2], v2 = xj[t + 2];
        const float4 u3 = xi[t + 3], v3 = xj[t + 3];
        a0 = fmaf(u0.x, v0.x, fmaf(u0.y, v0.y, fmaf(u0.z, v0.z, fmaf(u0.w, v0.w, a0))));
        a1 = fmaf(u1.x, v1.x, fmaf(u1.y, v1.y, fmaf(u1.z, v1.z, fmaf(u1.w, v1.w, a1))));
        a2 = fmaf(u2.x, v2.x, fmaf(u2.y, v2.y, fmaf(u2.z, v2.z, fmaf(u2.w, v2.w, a2))));
        a3 = fmaf(u3.x, v3.x, fmaf(u3.y, v3.y, fmaf(u3.z, v3.z, fmaf(u3.w, v3.w, a3))));
    }
    float dot = (a0 + a1) + (a2 + a3);
    dot += __shfl_xor(dot, 1);
    dot += __shfl_xor(dot, 2);
    const float d2x = (sqX[i] + sqX[jc]) - 2.0f * dot;
    unsigned long long key = ((unsigned long long)__float_as_uint(d2x) << 32) | (unsigned)jc;

    // exact top-5 by (d2, j): 5x u64 butterfly-min; 4 duplicate lanes collapse together
    float od[KNN]; int oi[KNN];
    #pragma unroll
    for (int k = 0; k < KNN; ++k) {
        unsigned long long m = key;
        #pragma unroll
        for (int off = 1; off < 64; off <<= 1) {
            const unsigned long long o = __shfl_xor(m, off);
            m = o < m ? o : m;
        }
        od[k] = __uint_as_float((uint32_t)(m >> 32));
        oi[k] = (int)(m & 0x1FFFull);
        if (key == m) key = 0xFFFFFFFFFFFFFFFFull;
    }

    // lid_X (quantile norm cancels in the log-ratio)
    const float l4 = log10f(sqrtf(fmaxf(od[KNN - 1], 0.0f)) + EPS);
    float lx = 0.0f;
    #pragma unroll
    for (int k = 0; k < KNN; ++k)
        lx -= (log10f(sqrtf(fmaxf(od[k], 0.0f)) + EPS) - l4);

    // z-distances at the 5 X-neighbors: lane k < 5 computes sum((zi-zj)^2)
    float lk = 0.0f;
    if (lane < KNN) {
        const int j = oi[lane];
        const float4* zi = (const float4*)(Z + (size_t)i * DZ);
        const float4* zj = (const float4*)(Z + (size_t)j * DZ);
        float s0 = 0.f, s1 = 0.f, s2 = 0.f, s3 = 0.f;
        #pragma unroll
        for (int t = 0; t < 16; t += 4) {
            const float4 u0 = zi[t],     v0 = zj[t];
            const float4 u1 = zi[t + 1], v1 = zj[t + 1];
            const float4 u2 = zi[t + 2], v2 = zj[t + 2];
            const float4 u3 = zi[t + 3], v3 = zj[t + 3];
            const float d0x = u0.x - v0.x, d0y = u0.y - v0.y, d0z = u0.z - v0.z, d0w = u0.w - v0.w;
            const float d1x = u1.x - v1.x, d1y = u1.y - v1.y, d1z = u1.z - v1.z, d1w = u1.w - v1.w;
            const float d2x_ = u2.x - v2.x, d2y = u2.y - v2.y, d2z_ = u2.z - v2.z, d2w = u2.w - v2.w;
            const float d3x = u3.x - v3.x, d3y = u3.y - v3.y, d3z = u3.z - v3.z, d3w = u3.w - v3.w;
            s0 = fmaf(d0x, d0x, fmaf(d0y, d0y, fmaf(d0z, d0z, fmaf(d0w, d0w, s0))));
            s1 = fmaf(d1x, d1x, fmaf(d1y, d1y, fmaf(d1z, d1z, fmaf(d1w, d1w, s1))));
            s2 = fmaf(d2x_, d2x_, fmaf(d2y, d2y, fmaf(d2z_, d2z_, fmaf(d2w, d2w, s2))));
            s3 = fmaf(d3x, d3x, fmaf(d3y, d3y, fmaf(d3z, d3z, fmaf(d3w, d3w, s3))));
        }
        const float d2z = (s0 + s1) + (s2 + s3);
        lk = log10f(sqrtf(fmaxf(d2z, 0.0f)) + EPS);
    }
    const float l4z = __shfl(lk, KNN - 1);
    float slk = 0.0f;
    #pragma unroll
    for (int m = 0; m < KNN; ++m) slk += __shfl(lk, m);

    if (lane == 0) {
        const float lz   = -(slk - (float)KNN * l4z);
        const float diff = lx - lz;
        wsum[wv] = diff * diff * (1.0f / ((float)NR * KNN * 10.0f));
    }
    __syncthreads();
    if (threadIdx.x == 0) {
        float s = 0.0f;
        #pragma unroll
        for (int t = 0; t < 16; ++t) s += wsum[t];
        atomicAdd(out, s);
    }
}

// ---------------------------------------------------------------- launch
extern "C" void kernel_launch(void* const* d_in, const int* in_sizes, int n_in,
                              void* d_out, int out_size, void* d_ws, size_t ws_size,
                              hipStream_t stream) {
    const float* X = (const float*)d_in[0];
    const float* Z = (const float*)d_in[1];
    float* out = (float*)d_out;

    char* ws = (char*)d_ws;
    float*     sqX      = (float*)ws;                         // 32 KB
    uint32_t*  partials = (uint32_t*)(ws + 32768);            // 8192*64*4 = 2 MB
    _Float16*  Xh       = (_Float16*)(ws + 32768 + 2097152);  // 4 MB

    split_k<<<NR / 4, 256, 0, stream>>>(X, Xh, sqX, out);
    mfma_topk_k<<<dim3(NR / RBLK, NSPLIT), 256, 0, stream>>>(Xh, sqX, partials);
    finalize_k<<<NR / 16, 1024, 0, stream>>>(partials, X, Z, sqX, out);
}

// Round 5
// 290.248 us; speedup vs baseline: 1.5000x; 1.5000x over previous
//
#include <hip/hip_runtime.h>
#include <math.h>
#include <stdint.h>

#define EPS     1e-7f
#define NR      8192
#define DX      256
#define DZ      64
#define KNN     5
#define KEEP    8               // per-split kept candidates (packed u32)
#define NPOOL   (NSPLIT * KEEP) // 64 = one per lane in finalize
#define NCAND   16              // exact-recompute pool in finalize
#define NSPLIT  8
#define JS      (NR / NSPLIT)   // 1024
#define JT      64              // j-cols staged per chunk
#define NCHUNK  (JS / JT)       // 16
#define RBLK    64              // i-rows per block

typedef _Float16 f16x8 __attribute__((ext_vector_type(8)));
typedef _Float16 f16x4 __attribute__((ext_vector_type(4)));
typedef float    f32x4 __attribute__((ext_vector_type(4)));

__device__ __forceinline__ uint32_t umin_(uint32_t a, uint32_t b) { return a < b ? a : b; }
__device__ __forceinline__ uint32_t umax_(uint32_t a, uint32_t b) { return a < b ? b : a; }

// ------------------------------------------------- X -> f16 + row sq-sums (+ zero out)
__global__ __launch_bounds__(256) void split_k(const float* __restrict__ X,
                                               _Float16* __restrict__ Xh,
                                               float* __restrict__ sqX,
                                               float* __restrict__ out) {
    if (blockIdx.x == 0 && threadIdx.x == 0) out[0] = 0.0f;  // finalize runs later on stream
    const int row  = blockIdx.x * 4 + (threadIdx.x >> 6);
    const int lane = threadIdx.x & 63;
    const float4 v = *(const float4*)&X[(size_t)row * DX + lane * 4];
    float s = v.x * v.x + v.y * v.y + v.z * v.z + v.w * v.w;
    f16x4 h;
    h[0] = (_Float16)v.x; h[1] = (_Float16)v.y;
    h[2] = (_Float16)v.z; h[3] = (_Float16)v.w;
    *(f16x4*)&Xh[(size_t)row * DX + lane * 4] = h;
    #pragma unroll
    for (int o = 32; o > 0; o >>= 1) s += __shfl_down(s, o);
    if (lane == 0) sqX[row] = s;
}

// ------------------------------------------------- f16 MFMA GEMM + fused packed top-5
// 4 waves/block. Wave w: rows half h=w>>1 (32 rows, A in regs), j-half sp=w&1.
// B staged via global_load_lds (16B) with source-side XOR swizzle. Candidates packed
// (d2_bits & ~0x1FFF)|j -> u32 min chains; exact fp32 re-rank in finalize fixes quantization.
// NOTE: __launch_bounds__(256,2) — NOT (256,4): min-waves 4 clamps VGPR to 64 and the
// A-fragments + top-k state spill to scratch (R4: WRITE_SIZE 1 MB -> 1.07 GB, 330 us).
// At 92 VGPR the HW reaches 16 waves/CU on its own (LDS 35 KB -> 4 blocks/CU, grid 1024).
__global__ __launch_bounds__(256, 2) void mfma_topk_k(const _Float16* __restrict__ Xh,
                                                      const float* __restrict__ sqX,
                                                      uint32_t* __restrict__ partials) {
    __shared__ __align__(16) uint8_t smem[32768];      // B staging: 2048 slots x 16 B
    __shared__ uint32_t mb2[RBLK][2][KNN];             // cross-wave merge (2.5 KB)
    f16x8* BhV = (f16x8*)smem;

    const int tid  = threadIdx.x;
    const int w    = tid >> 6;
    const int lane = tid & 63;
    const int n    = lane & 15;
    const int quad = lane >> 4;
    const int x7   = n & 7;
    const int h    = w >> 1;
    const int sp   = w & 1;
    const int ib   = blockIdx.x * RBLK;
    const int jb0  = blockIdx.y * JS;
    const int rowbase = ib + h * 32;

    // A fragments: 2 rowgroups x 8 k-steps (A layout: row=lane&15, k=quad*8+j)
    f16x8 Ah[2][8];
    #pragma unroll
    for (int g = 0; g < 2; ++g)
        #pragma unroll
        for (int ks = 0; ks < 8; ++ks)
            Ah[g][ks] = *(const f16x8*)(Xh + (size_t)(rowbase + g * 16 + n) * DX + ks * 32 + quad * 8);

    float sqi[2][4];
    #pragma unroll
    for (int g = 0; g < 2; ++g) {
        const float4 t = *(const float4*)&sqX[rowbase + g * 16 + quad * 4];
        sqi[g][0] = t.x; sqi[g][1] = t.y; sqi[g][2] = t.z; sqi[g][3] = t.w;
    }

    uint32_t best[8][KNN];   // q = g*4+r; ascending
    #pragma unroll
    for (int q = 0; q < 8; ++q)
        #pragma unroll
        for (int k = 0; k < KNN; ++k) best[q][k] = 0xFFFFFFFFu;

    // staging source map: slot q = w*512 + u*64 + lane holds row sj=q>>5, chunk c=(q&31)^(sj&7)
    int srcoff[8];
    #pragma unroll
    for (int u = 0; u < 8; ++u) {
        const int q  = w * 512 + u * 64 + lane;
        const int sj = q >> 5;
        const int c  = (q & 31) ^ (sj & 7);
        srcoff[u] = sj * DX + c * 8;
    }

    for (int jc = 0; jc < NCHUNK; ++jc) {
        const int jb = jb0 + jc * JT;
        __syncthreads();  // previous chunk's readers done
        #pragma unroll
        for (int u = 0; u < 8; ++u) {
            const _Float16* src = Xh + (size_t)jb * DX + srcoff[u];
            uint8_t* dst = smem + (size_t)(w * 512 + u * 64) * 16;  // wave-uniform; HW adds lane*16
            __builtin_amdgcn_global_load_lds((const __attribute__((address_space(1))) uint32_t*)src,
                                             (__attribute__((address_space(3))) uint32_t*)dst,
                                             16, 0, 0);
        }
        __syncthreads();  // drains vmcnt -> staging visible

        f32x4 acc[2][2];  // [si][g]
        #pragma unroll
        for (int si = 0; si < 2; ++si)
            #pragma unroll
            for (int g = 0; g < 2; ++g)
                #pragma unroll
                for (int r = 0; r < 4; ++r) acc[si][g][r] = 0.0f;

        #pragma unroll
        for (int ks = 0; ks < 8; ++ks) {
            #pragma unroll
            for (int si = 0; si < 2; ++si) {
                const int s   = sp * 2 + si;
                const int idx = (s * 16 + n) * 32 + ((ks * 4 + quad) ^ x7);
                const f16x8 b = BhV[idx];
                acc[si][0] = __builtin_amdgcn_mfma_f32_16x16x32_f16(Ah[0][ks], b, acc[si][0], 0, 0, 0);
                acc[si][1] = __builtin_amdgcn_mfma_f32_16x16x32_f16(Ah[1][ks], b, acc[si][1], 0, 0, 0);
            }
        }

        // fold 16 candidates/lane (C layout: col=n, row=quad*4+reg)
        #pragma unroll
        for (int si = 0; si < 2; ++si) {
            const int j = jb + (sp * 2 + si) * 16 + n;
            const float sqj = sqX[j];
            #pragma unroll
            for (int g = 0; g < 2; ++g) {
                #pragma unroll
                for (int r = 0; r < 4; ++r) {
                    const int i = rowbase + g * 16 + quad * 4 + r;
                    if (j == i) continue;  // reference drops the diagonal
                    const float d2 = (sqi[g][r] + sqj) - 2.0f * acc[si][g][r];
                    const uint32_t cand = (__float_as_uint(d2) & 0xFFFFE000u) | (uint32_t)j;
                    const int q = g * 4 + r;
                    if (cand < best[q][KNN - 1]) {
                        uint32_t ck = cand;
                        #pragma unroll
                        for (int k = 0; k < KNN; ++k) {
                            const uint32_t bk = best[q][k];
                            best[q][k] = umin_(ck, bk); ck = umax_(ck, bk);
                        }
                    }
                }
            }
        }
    }

    // wave-internal merge across the 16 n-lanes (rows live in a fixed quad-group):
    // sorted-merge identity c_k = min(b_k, max(a_0,b_{k-1}), ..., max(a_{k-1},b_0), a_k)
    #pragma unroll
    for (int mask = 1; mask <= 8; mask <<= 1) {
        #pragma unroll
        for (int q = 0; q < 8; ++q) {
            uint32_t a0 = best[q][0], a1 = best[q][1], a2 = best[q][2], a3 = best[q][3], a4 = best[q][4];
            const uint32_t b0 = __shfl_xor(a0, mask);
            const uint32_t b1 = __shfl_xor(a1, mask);
            const uint32_t b2 = __shfl_xor(a2, mask);
            const uint32_t b3 = __shfl_xor(a3, mask);
            const uint32_t b4 = __shfl_xor(a4, mask);
            best[q][0] = umin_(a0, b0);
            best[q][1] = umin_(umin_(a1, b1), umax_(a0, b0));
            best[q][2] = umin_(umin_(a2, b2), umin_(umax_(a0, b1), umax_(a1, b0)));
            best[q][3] = umin_(umin_(a3, b3),
                               umin_(umax_(a1, b1), umin_(umax_(a0, b2), umax_(a2, b0))));
            best[q][4] = umin_(umin_(a4, b4),
                               umin_(umin_(umax_(a0, b3), umax_(a1, b2)),
                                     umin_(umax_(a2, b1), umax_(a3, b0))));
        }
    }

    // cross-wave (sp) merge via tiny padded LDS; emit KEEP=8 per row per split
    if (n < KNN) {
        #pragma unroll
        for (int q = 0; q < 8; ++q) {
            const int rloc = h * 32 + (q >> 2) * 16 + quad * 4 + (q & 3);
            mb2[rloc][sp][n] = best[q][n];
        }
    }
    __syncthreads();
    if (tid < RBLK) {
        uint32_t a0 = mb2[tid][0][0], a1 = mb2[tid][0][1], a2 = mb2[tid][0][2],
                 a3 = mb2[tid][0][3], a4 = mb2[tid][0][4];
        uint32_t b0 = mb2[tid][1][0], b1 = mb2[tid][1][1], b2 = mb2[tid][1][2],
                 b3 = mb2[tid][1][3], b4 = mb2[tid][1][4];
        uint32_t o[KEEP];
        o[0] = umin_(a0, b0);
        o[1] = umin_(umin_(a1, b1), umax_(a0, b0));
        o[2] = umin_(umin_(a2, b2), umin_(umax_(a0, b1), umax_(a1, b0)));
        o[3] = umin_(umin_(a3, b3), umin_(umax_(a1, b1), umin_(umax_(a0, b2), umax_(a2, b0))));
        o[4] = umin_(umin_(a4, b4), umin_(umin_(umax_(a0, b3), umax_(a1, b2)),
                                          umin_(umax_(a2, b1), umax_(a3, b0))));
        o[5] = umin_(umin_(umax_(a0, b4), umax_(a4, b0)),
                     umin_(umax_(a1, b3), umin_(umax_(a2, b2), umax_(a3, b1))));
        o[6] = umin_(umin_(umax_(a1, b4), umax_(a4, b1)),
                     umin_(umax_(a2, b3), umax_(a3, b2)));
        o[7] = umin_(umax_(a2, b4), umin_(umax_(a3, b3), umax_(a4, b2)));
        #pragma unroll
        for (int k = 0; k < KEEP; ++k)
            partials[(size_t)(ib + tid) * NPOOL + blockIdx.y * KEEP + k] = o[k];
    }
}

// ------------------------------------------------- one wave per row: approx-rank prefilter
// (64-pool = 1/lane), exact fp32 re-rank (16 cand x 4 lanes), lid, loss
__global__ __launch_bounds__(1024) void finalize_k(const uint32_t* __restrict__ parts,
                                                   const float* __restrict__ X,
                                                   const float* __restrict__ Z,
                                                   const float* __restrict__ sqX,
                                                   float* __restrict__ out) {
    __shared__ uint32_t jl[16][NCAND];
    __shared__ float wsum[16];
    const int wv   = threadIdx.x >> 6;
    const int lane = threadIdx.x & 63;
    const int i    = blockIdx.x * 16 + wv;

    // rank the 64 packed candidates (splits disjoint -> keys distinct)
    const uint32_t packed = parts[(size_t)i * NPOOL + lane];
    int rank = 0;
    #pragma unroll
    for (int m = 0; m < 64; ++m) {
        const uint32_t v = __shfl(packed, m);
        rank += (v < packed) || (v == packed && m < lane);
    }
    if (rank < NCAND) jl[wv][rank] = packed & 0x1FFFu;
    __syncthreads();

    // exact fp32 d2: candidate c = lane>>2, quarter = lane&3 (64-dim slice each)
    const int c = lane >> 2, qtr = lane & 3;
    const int jc = (int)jl[wv][c];
    const float4* xi = (const float4*)(X + (size_t)i * DX) + qtr * 16;
    const float4* xj = (const float4*)(X + (size_t)jc * DX) + qtr * 16;
    float a0 = 0.f, a1 = 0.f, a2 = 0.f, a3 = 0.f;
    #pragma unroll
    for (int t = 0; t < 16; t += 4) {
        const float4 u0 = xi[t],     v0 = xj[t];
        const float4 u1 = xi[t + 1], v1 = xj[t + 1];
        const float4 u2 = xi[t + 2], v2 = xj[t + 2];
        const float4 u3 = xi[t + 3], v3 = xj[t + 3];
        a0 = fmaf(u0.x, v0.x, fmaf(u0.y, v0.y, fmaf(u0.z, v0.z, fmaf(u0.w, v0.w, a0))));
        a1 = fmaf(u1.x, v1.x, fmaf(u1.y, v1.y, fmaf(u1.z, v1.z, fmaf(u1.w, v1.w, a1))));
        a2 = fmaf(u2.x, v2.x, fmaf(u2.y, v2.y, fmaf(u2.z, v2.z, fmaf(u2.w, v2.w, a2))));
        a3 = fmaf(u3.x, v3.x, fmaf(u3.y, v3.y, fmaf(u3.z, v3.z, fmaf(u3.w, v3.w, a3))));
    }
    float dot = (a0 + a1) + (a2 + a3);
    dot += __shfl_xor(dot, 1);
    dot += __shfl_xor(dot, 2);
    const float d2x = (sqX[i] + sqX[jc]) - 2.0f * dot;
    unsigned long long key = ((unsigned long long)__float_as_uint(d2x) << 32) | (unsigned)jc;

    // exact top-5 by (d2, j): 5x u64 butterfly-min; 4 duplicate lanes collapse together
    float od[KNN]; int oi[KNN];
    #pragma unroll
    for (int k = 0; k < KNN; ++k) {
        unsigned long long m = key;
        #pragma unroll
        for (int off = 1; off < 64; off <<= 1) {
            const unsigned long long o = __shfl_xor(m, off);
            m = o < m ? o : m;
        }
        od[k] = __uint_as_float((uint32_t)(m >> 32));
        oi[k] = (int)(m & 0x1FFFull);
        if (key == m) key = 0xFFFFFFFFFFFFFFFFull;
    }

    // lid_X (quantile norm cancels in the log-ratio)
    const float l4 = log10f(sqrtf(fmaxf(od[KNN - 1], 0.0f)) + EPS);
    float lx = 0.0f;
    #pragma unroll
    for (int k = 0; k < KNN; ++k)
        lx -= (log10f(sqrtf(fmaxf(od[k], 0.0f)) + EPS) - l4);

    // z-distances at the 5 X-neighbors: lane k < 5 computes sum((zi-zj)^2)
    float lk = 0.0f;
    if (lane < KNN) {
        const int j = oi[lane];
        const float4* zi = (const float4*)(Z + (size_t)i * DZ);
        const float4* zj = (const float4*)(Z + (size_t)j * DZ);
        float s0 = 0.f, s1 = 0.f, s2 = 0.f, s3 = 0.f;
        #pragma unroll
        for (int t = 0; t < 16; t += 4) {
            const float4 u0 = zi[t],     v0 = zj[t];
            const float4 u1 = zi[t + 1], v1 = zj[t + 1];
            const float4 u2 = zi[t + 2], v2 = zj[t + 2];
            const float4 u3 = zi[t + 3], v3 = zj[t + 3];
            const float d0x = u0.x - v0.x, d0y = u0.y - v0.y, d0z = u0.z - v0.z, d0w = u0.w - v0.w;
            const float d1x = u1.x - v1.x, d1y = u1.y - v1.y, d1z = u1.z - v1.z, d1w = u1.w - v1.w;
            const float d2x_ = u2.x - v2.x, d2y = u2.y - v2.y, d2z_ = u2.z - v2.z, d2w = u2.w - v2.w;
            const float d3x = u3.x - v3.x, d3y = u3.y - v3.y, d3z = u3.z - v3.z, d3w = u3.w - v3.w;
            s0 = fmaf(d0x, d0x, fmaf(d0y, d0y, fmaf(d0z, d0z, fmaf(d0w, d0w, s0))));
            s1 = fmaf(d1x, d1x, fmaf(d1y, d1y, fmaf(d1z, d1z, fmaf(d1w, d1w, s1))));
            s2 = fmaf(d2x_, d2x_, fmaf(d2y, d2y, fmaf(d2z_, d2z_, fmaf(d2w, d2w, s2))));
            s3 = fmaf(d3x, d3x, fmaf(d3y, d3y, fmaf(d3z, d3z, fmaf(d3w, d3w, s3))));
        }
        const float d2z = (s0 + s1) + (s2 + s3);
        lk = log10f(sqrtf(fmaxf(d2z, 0.0f)) + EPS);
    }
    const float l4z = __shfl(lk, KNN - 1);
    float slk = 0.0f;
    #pragma unroll
    for (int m = 0; m < KNN; ++m) slk += __shfl(lk, m);

    if (lane == 0) {
        const float lz   = -(slk - (float)KNN * l4z);
        const float diff = lx - lz;
        wsum[wv] = diff * diff * (1.0f / ((float)NR * KNN * 10.0f));
    }
    __syncthreads();
    if (threadIdx.x == 0) {
        float s = 0.0f;
        #pragma unroll
        for (int t = 0; t < 16; ++t) s += wsum[t];
        atomicAdd(out, s);
    }
}

// ---------------------------------------------------------------- launch
extern "C" void kernel_launch(void* const* d_in, const int* in_sizes, int n_in,
                              void* d_out, int out_size, void* d_ws, size_t ws_size,
                              hipStream_t stream) {
    const float* X = (const float*)d_in[0];
    const float* Z = (const float*)d_in[1];
    float* out = (float*)d_out;

    char* ws = (char*)d_ws;
    float*     sqX      = (float*)ws;                         // 32 KB
    uint32_t*  partials = (uint32_t*)(ws + 32768);            // 8192*64*4 = 2 MB
    _Float16*  Xh       = (_Float16*)(ws + 32768 + 2097152);  // 4 MB

    split_k<<<NR / 4, 256, 0, stream>>>(X, Xh, sqX, out);
    mfma_topk_k<<<dim3(NR / RBLK, NSPLIT), 256, 0, stream>>>(Xh, sqX, partials);
    finalize_k<<<NR / 16, 1024, 0, stream>>>(partials, X, Z, sqX, out);
}

// Round 6
// 199.924 us; speedup vs baseline: 2.1777x; 1.4518x over previous
//
#include <hip/hip_runtime.h>
#include <math.h>
#include <stdint.h>

#define EPS     1e-7f
#define NR      8192
#define DX      256
#define DZ      64
#define KNN     5
#define KEEP    8               // per-split kept candidates (packed u32)
#define NPOOL   (NSPLIT * KEEP) // 64 = one per lane in finalize
#define NCAND   16              // exact-recompute pool in finalize
#define NSPLIT  8
#define JS      (NR / NSPLIT)   // 1024
#define JT      64              // j-cols staged per chunk
#define NCHUNK  (JS / JT)       // 16
#define RBLK    64              // i-rows per block

typedef _Float16 f16x8 __attribute__((ext_vector_type(8)));
typedef _Float16 f16x4 __attribute__((ext_vector_type(4)));
typedef float    f32x4 __attribute__((ext_vector_type(4)));

__device__ __forceinline__ uint32_t umin_(uint32_t a, uint32_t b) { return a < b ? a : b; }
__device__ __forceinline__ uint32_t umax_(uint32_t a, uint32_t b) { return a < b ? b : a; }

// ------------------------------------------------- X -> f16 + row sq-sums (+ zero out)
__global__ __launch_bounds__(256) void split_k(const float* __restrict__ X,
                                               _Float16* __restrict__ Xh,
                                               float* __restrict__ sqX,
                                               float* __restrict__ out) {
    if (blockIdx.x == 0 && threadIdx.x == 0) out[0] = 0.0f;  // finalize runs later on stream
    const int row  = blockIdx.x * 4 + (threadIdx.x >> 6);
    const int lane = threadIdx.x & 63;
    const float4 v = *(const float4*)&X[(size_t)row * DX + lane * 4];
    float s = v.x * v.x + v.y * v.y + v.z * v.z + v.w * v.w;
    f16x4 h;
    h[0] = (_Float16)v.x; h[1] = (_Float16)v.y;
    h[2] = (_Float16)v.z; h[3] = (_Float16)v.w;
    *(f16x4*)&Xh[(size_t)row * DX + lane * 4] = h;
    #pragma unroll
    for (int o = 32; o > 0; o >>= 1) s += __shfl_down(s, o);
    if (lane == 0) sqX[row] = s;
}

// ------------------------------------------------- f16 MFMA GEMM + fused packed top-5
// 4 waves/block. Wave w: rows half h=w>>1 (32 rows, A in regs), j-half sp=w&1.
// B staged via global_load_lds (16B) with source-side XOR swizzle. Candidates packed
// (d2_bits & ~0x1FFF)|j -> u32 min chains; exact fp32 re-rank in finalize fixes quantization.
// CORRECTNESS/PERF NOTES (hard-won):
//  * __launch_bounds__(256,2), NOT (256,4): min-waves 4 clamps VGPR to 64 -> scratch spill
//    (R4: WRITE_SIZE 1 MB -> 1.07 GB).
//  * NO runtime subscripts into register arrays (best[q][n] with runtime n): forces the
//    whole array to scratch for the kernel lifetime (R5: WRITE_SIZE 711 MB). Dump via
//    constant-index select chains only.
__global__ __launch_bounds__(256, 2) void mfma_topk_k(const _Float16* __restrict__ Xh,
                                                      const float* __restrict__ sqX,
                                                      uint32_t* __restrict__ partials) {
    __shared__ __align__(16) uint8_t smem[32768];      // B staging: 2048 slots x 16 B
    __shared__ uint32_t mb2[RBLK][2][KNN];             // cross-wave merge (2.5 KB)
    f16x8* BhV = (f16x8*)smem;

    const int tid  = threadIdx.x;
    const int w    = tid >> 6;
    const int lane = tid & 63;
    const int n    = lane & 15;
    const int quad = lane >> 4;
    const int x7   = n & 7;
    const int h    = w >> 1;
    const int sp   = w & 1;
    const int ib   = blockIdx.x * RBLK;
    const int jb0  = blockIdx.y * JS;
    const int rowbase = ib + h * 32;

    // A fragments: 2 rowgroups x 8 k-steps (A layout: row=lane&15, k=quad*8+j)
    f16x8 Ah[2][8];
    #pragma unroll
    for (int g = 0; g < 2; ++g)
        #pragma unroll
        for (int ks = 0; ks < 8; ++ks)
            Ah[g][ks] = *(const f16x8*)(Xh + (size_t)(rowbase + g * 16 + n) * DX + ks * 32 + quad * 8);

    float sqi[2][4];
    #pragma unroll
    for (int g = 0; g < 2; ++g) {
        const float4 t = *(const float4*)&sqX[rowbase + g * 16 + quad * 4];
        sqi[g][0] = t.x; sqi[g][1] = t.y; sqi[g][2] = t.z; sqi[g][3] = t.w;
    }

    uint32_t best[8][KNN];   // q = g*4+r; ascending; ALL indices compile-time constants
    #pragma unroll
    for (int q = 0; q < 8; ++q)
        #pragma unroll
        for (int k = 0; k < KNN; ++k) best[q][k] = 0xFFFFFFFFu;

    // staging source map: slot q = w*512 + u*64 + lane holds row sj=q>>5, chunk c=(q&31)^(sj&7)
    int srcoff[8];
    #pragma unroll
    for (int u = 0; u < 8; ++u) {
        const int q  = w * 512 + u * 64 + lane;
        const int sj = q >> 5;
        const int c  = (q & 31) ^ (sj & 7);
        srcoff[u] = sj * DX + c * 8;
    }

    for (int jc = 0; jc < NCHUNK; ++jc) {
        const int jb = jb0 + jc * JT;
        __syncthreads();  // previous chunk's readers done
        #pragma unroll
        for (int u = 0; u < 8; ++u) {
            const _Float16* src = Xh + (size_t)jb * DX + srcoff[u];
            uint8_t* dst = smem + (size_t)(w * 512 + u * 64) * 16;  // wave-uniform; HW adds lane*16
            __builtin_amdgcn_global_load_lds((const __attribute__((address_space(1))) uint32_t*)src,
                                             (__attribute__((address_space(3))) uint32_t*)dst,
                                             16, 0, 0);
        }
        __syncthreads();  // drains vmcnt -> staging visible

        f32x4 acc[2][2];  // [si][g]
        #pragma unroll
        for (int si = 0; si < 2; ++si)
            #pragma unroll
            for (int g = 0; g < 2; ++g)
                #pragma unroll
                for (int r = 0; r < 4; ++r) acc[si][g][r] = 0.0f;

        #pragma unroll
        for (int ks = 0; ks < 8; ++ks) {
            #pragma unroll
            for (int si = 0; si < 2; ++si) {
                const int s   = sp * 2 + si;
                const int idx = (s * 16 + n) * 32 + ((ks * 4 + quad) ^ x7);
                const f16x8 b = BhV[idx];
                acc[si][0] = __builtin_amdgcn_mfma_f32_16x16x32_f16(Ah[0][ks], b, acc[si][0], 0, 0, 0);
                acc[si][1] = __builtin_amdgcn_mfma_f32_16x16x32_f16(Ah[1][ks], b, acc[si][1], 0, 0, 0);
            }
        }

        // fold 16 candidates/lane (C layout: col=n, row=quad*4+reg)
        #pragma unroll
        for (int si = 0; si < 2; ++si) {
            const int j = jb + (sp * 2 + si) * 16 + n;
            const float sqj = sqX[j];
            #pragma unroll
            for (int g = 0; g < 2; ++g) {
                #pragma unroll
                for (int r = 0; r < 4; ++r) {
                    const int i = rowbase + g * 16 + quad * 4 + r;
                    if (j == i) continue;  // reference drops the diagonal
                    const float d2 = (sqi[g][r] + sqj) - 2.0f * acc[si][g][r];
                    const uint32_t cand = (__float_as_uint(d2) & 0xFFFFE000u) | (uint32_t)j;
                    const int q = g * 4 + r;
                    if (cand < best[q][KNN - 1]) {
                        uint32_t ck = cand;
                        #pragma unroll
                        for (int k = 0; k < KNN; ++k) {
                            const uint32_t bk = best[q][k];
                            best[q][k] = umin_(ck, bk); ck = umax_(ck, bk);
                        }
                    }
                }
            }
        }
    }

    // per-q: butterfly-merge sorted-5 across the 16 n-lanes, then immediate LDS dump
    // (constant-index selects only; frees best[q] early -> low register pressure)
    #pragma unroll
    for (int q = 0; q < 8; ++q) {
        uint32_t a0 = best[q][0], a1 = best[q][1], a2 = best[q][2],
                 a3 = best[q][3], a4 = best[q][4];
        #pragma unroll
        for (int mask = 1; mask <= 8; mask <<= 1) {
            const uint32_t b0 = __shfl_xor(a0, mask);
            const uint32_t b1 = __shfl_xor(a1, mask);
            const uint32_t b2 = __shfl_xor(a2, mask);
            const uint32_t b3 = __shfl_xor(a3, mask);
            const uint32_t b4 = __shfl_xor(a4, mask);
            const uint32_t c0 = umin_(a0, b0);
            const uint32_t c1 = umin_(umin_(a1, b1), umax_(a0, b0));
            const uint32_t c2 = umin_(umin_(a2, b2), umin_(umax_(a0, b1), umax_(a1, b0)));
            const uint32_t c3 = umin_(umin_(a3, b3),
                                      umin_(umax_(a1, b1), umin_(umax_(a0, b2), umax_(a2, b0))));
            const uint32_t c4 = umin_(umin_(a4, b4),
                                      umin_(umin_(umax_(a0, b3), umax_(a1, b2)),
                                            umin_(umax_(a2, b1), umax_(a3, b0))));
            a0 = c0; a1 = c1; a2 = c2; a3 = c3; a4 = c4;
        }
        const int rloc = h * 32 + (q >> 2) * 16 + quad * 4 + (q & 3);
        uint32_t v = a0;                 // lane n gets element n via select chain
        v = (n == 1) ? a1 : v;
        v = (n == 2) ? a2 : v;
        v = (n == 3) ? a3 : v;
        v = (n == 4) ? a4 : v;
        if (n < KNN) mb2[rloc][sp][n] = v;
    }
    __syncthreads();

    // cross-wave (sp) merge; emit KEEP=8 per row per split
    if (tid < RBLK) {
        const uint32_t a0 = mb2[tid][0][0], a1 = mb2[tid][0][1], a2 = mb2[tid][0][2],
                       a3 = mb2[tid][0][3], a4 = mb2[tid][0][4];
        const uint32_t b0 = mb2[tid][1][0], b1 = mb2[tid][1][1], b2 = mb2[tid][1][2],
                       b3 = mb2[tid][1][3], b4 = mb2[tid][1][4];
        uint32_t o[KEEP];
        o[0] = umin_(a0, b0);
        o[1] = umin_(umin_(a1, b1), umax_(a0, b0));
        o[2] = umin_(umin_(a2, b2), umin_(umax_(a0, b1), umax_(a1, b0)));
        o[3] = umin_(umin_(a3, b3), umin_(umax_(a1, b1), umin_(umax_(a0, b2), umax_(a2, b0))));
        o[4] = umin_(umin_(a4, b4), umin_(umin_(umax_(a0, b3), umax_(a1, b2)),
                                          umin_(umax_(a2, b1), umax_(a3, b0))));
        o[5] = umin_(umin_(umax_(a0, b4), umax_(a4, b0)),
                     umin_(umax_(a1, b3), umin_(umax_(a2, b2), umax_(a3, b1))));
        o[6] = umin_(umin_(umax_(a1, b4), umax_(a4, b1)),
                     umin_(umax_(a2, b3), umax_(a3, b2)));
        o[7] = umin_(umax_(a2, b4), umin_(umax_(a3, b3), umax_(a4, b2)));
        #pragma unroll
        for (int k = 0; k < KEEP; ++k)
            partials[(size_t)(ib + tid) * NPOOL + blockIdx.y * KEEP + k] = o[k];
    }
}

// ------------------------------------------------- one wave per row: approx-rank prefilter
// (64-pool = 1/lane), exact fp32 re-rank (16 cand x 4 lanes), lid, loss
__global__ __launch_bounds__(1024) void finalize_k(const uint32_t* __restrict__ parts,
                                                   const float* __restrict__ X,
                                                   const float* __restrict__ Z,
                                                   const float* __restrict__ sqX,
                                                   float* __restrict__ out) {
    __shared__ uint32_t jl[16][NCAND];
    __shared__ float wsum[16];
    const int wv   = threadIdx.x >> 6;
    const int lane = threadIdx.x & 63;
    const int i    = blockIdx.x * 16 + wv;

    // rank the 64 packed candidates (splits disjoint -> keys distinct)
    const uint32_t packed = parts[(size_t)i * NPOOL + lane];
    int rank = 0;
    #pragma unroll
    for (int m = 0; m < 64; ++m) {
        const uint32_t v = __shfl(packed, m);
        rank += (v < packed) || (v == packed && m < lane);
    }
    if (rank < NCAND) jl[wv][rank] = packed & 0x1FFFu;
    __syncthreads();

    // exact fp32 d2: candidate c = lane>>2, quarter = lane&3 (64-dim slice each)
    const int c = lane >> 2, qtr = lane & 3;
    const int jc = (int)jl[wv][c];
    const float4* xi = (const float4*)(X + (size_t)i * DX) + qtr * 16;
    const float4* xj = (const float4*)(X + (size_t)jc * DX) + qtr * 16;
    float a0 = 0.f, a1 = 0.f, a2 = 0.f, a3 = 0.f;
    #pragma unroll
    for (int t = 0; t < 16; t += 4) {
        const float4 u0 = xi[t],     v0 = xj[t];
        const float4 u1 = xi[t + 1], v1 = xj[t + 1];
        const float4 u2 = xi[t + 2], v2 = xj[t + 2];
        const float4 u3 = xi[t + 3], v3 = xj[t + 3];
        a0 = fmaf(u0.x, v0.x, fmaf(u0.y, v0.y, fmaf(u0.z, v0.z, fmaf(u0.w, v0.w, a0))));
        a1 = fmaf(u1.x, v1.x, fmaf(u1.y, v1.y, fmaf(u1.z, v1.z, fmaf(u1.w, v1.w, a1))));
        a2 = fmaf(u2.x, v2.x, fmaf(u2.y, v2.y, fmaf(u2.z, v2.z, fmaf(u2.w, v2.w, a2))));
        a3 = fmaf(u3.x, v3.x, fmaf(u3.y, v3.y, fmaf(u3.z, v3.z, fmaf(u3.w, v3.w, a3))));
    }
    float dot = (a0 + a1) + (a2 + a3);
    dot += __shfl_xor(dot, 1);
    dot += __shfl_xor(dot, 2);
    const float d2x = (sqX[i] + sqX[jc]) - 2.0f * dot;
    unsigned long long key = ((unsigned long long)__float_as_uint(d2x) << 32) | (unsigned)jc;

    // exact top-5 by (d2, j): 5x u64 butterfly-min; 4 duplicate lanes collapse together
    // (od/oi kept constant-indexed; lane-dependent reads below use select chains)
    float od[KNN]; int oi[KNN];
    #pragma unroll
    for (int k = 0; k < KNN; ++k) {
        unsigned long long m = key;
        #pragma unroll
        for (int off = 1; off < 64; off <<= 1) {
            const unsigned long long o = __shfl_xor(m, off);
            m = o < m ? o : m;
        }
        od[k] = __uint_as_float((uint32_t)(m >> 32));
        oi[k] = (int)(m & 0x1FFFull);
        if (key == m) key = 0xFFFFFFFFFFFFFFFFull;
    }

    // lid_X (quantile norm cancels in the log-ratio)
    const float l4 = log10f(sqrtf(fmaxf(od[KNN - 1], 0.0f)) + EPS);
    float lx = 0.0f;
    #pragma unroll
    for (int k = 0; k < KNN; ++k)
        lx -= (log10f(sqrtf(fmaxf(od[k], 0.0f)) + EPS) - l4);

    // z-distances at the 5 X-neighbors: lane k < 5 computes sum((zi-zj)^2)
    int jz = oi[0];                      // constant-index select chain (no oi[lane]!)
    jz = (lane == 1) ? oi[1] : jz;
    jz = (lane == 2) ? oi[2] : jz;
    jz = (lane == 3) ? oi[3] : jz;
    jz = (lane == 4) ? oi[4] : jz;
    float lk = 0.0f;
    if (lane < KNN) {
        const float4* zi = (const float4*)(Z + (size_t)i * DZ);
        const float4* zj = (const float4*)(Z + (size_t)jz * DZ);
        float s0 = 0.f, s1 = 0.f, s2 = 0.f, s3 = 0.f;
        #pragma unroll
        for (int t = 0; t < 16; t += 4) {
            const float4 u0 = zi[t],     v0 = zj[t];
            const float4 u1 = zi[t + 1], v1 = zj[t + 1];
            const float4 u2 = zi[t + 2], v2 = zj[t + 2];
            const float4 u3 = zi[t + 3], v3 = zj[t + 3];
            const float d0x = u0.x - v0.x, d0y = u0.y - v0.y, d0z = u0.z - v0.z, d0w = u0.w - v0.w;
            const float d1x = u1.x - v1.x, d1y = u1.y - v1.y, d1z = u1.z - v1.z, d1w = u1.w - v1.w;
            const float d2x_ = u2.x - v2.x, d2y = u2.y - v2.y, d2z_ = u2.z - v2.z, d2w = u2.w - v2.w;
            const float d3x = u3.x - v3.x, d3y = u3.y - v3.y, d3z = u3.z - v3.z, d3w = u3.w - v3.w;
            s0 = fmaf(d0x, d0x, fmaf(d0y, d0y, fmaf(d0z, d0z, fmaf(d0w, d0w, s0))));
            s1 = fmaf(d1x, d1x, fmaf(d1y, d1y, fmaf(d1z, d1z, fmaf(d1w, d1w, s1))));
            s2 = fmaf(d2x_, d2x_, fmaf(d2y, d2y, fmaf(d2z_, d2z_, fmaf(d2w, d2w, s2))));
            s3 = fmaf(d3x, d3x, fmaf(d3y, d3y, fmaf(d3z, d3z, fmaf(d3w, d3w, s3))));
        }
        const float d2z = (s0 + s1) + (s2 + s3);
        lk = log10f(sqrtf(fmaxf(d2z, 0.0f)) + EPS);
    }
    const float l4z = __shfl(lk, KNN - 1);
    float slk = 0.0f;
    #pragma unroll
    for (int m = 0; m < KNN; ++m) slk += __shfl(lk, m);

    if (lane == 0) {
        const float lz   = -(slk - (float)KNN * l4z);
        const float diff = lx - lz;
        wsum[wv] = diff * diff * (1.0f / ((float)NR * KNN * 10.0f));
    }
    __syncthreads();
    if (threadIdx.x == 0) {
        float s = 0.0f;
        #pragma unroll
        for (int t = 0; t < 16; ++t) s += wsum[t];
        atomicAdd(out, s);
    }
}

// ---------------------------------------------------------------- launch
extern "C" void kernel_launch(void* const* d_in, const int* in_sizes, int n_in,
                              void* d_out, int out_size, void* d_ws, size_t ws_size,
                              hipStream_t stream) {
    const float* X = (const float*)d_in[0];
    const float* Z = (const float*)d_in[1];
    float* out = (float*)d_out;

    char* ws = (char*)d_ws;
    float*     sqX      = (float*)ws;                         // 32 KB
    uint32_t*  partials = (uint32_t*)(ws + 32768);            // 8192*64*4 = 2 MB
    _Float16*  Xh       = (_Float16*)(ws + 32768 + 2097152);  // 4 MB

    split_k<<<NR / 4, 256, 0, stream>>>(X, Xh, sqX, out);
    mfma_topk_k<<<dim3(NR / RBLK, NSPLIT), 256, 0, stream>>>(Xh, sqX, partials);
    finalize_k<<<NR / 16, 1024, 0, stream>>>(partials, X, Z, sqX, out);
}

// Round 7
// 198.671 us; speedup vs baseline: 2.1914x; 1.0063x over previous
//
#include <hip/hip_runtime.h>
#include <math.h>
#include <stdint.h>

#define EPS     1e-7f
#define NR      8192
#define DX      256
#define DZ      64
#define KNN     5
#define KEEP    8               // per-split kept candidates (packed u32)
#define NSPLIT  8
#define NPOOL   (NSPLIT * KEEP) // 64 = one per lane in finalize
#define JS      (NR / NSPLIT)   // 1024
#define JT      32              // j-cols staged per chunk (double-buffered)
#define NCHUNK  (JS / JT)       // 32
#define RBLK    64              // i-rows per block
#define BUFB    16384           // bytes per staging buffer (32 rows x 256 k x 2 B)

typedef _Float16 f16x8 __attribute__((ext_vector_type(8)));
typedef _Float16 f16x4 __attribute__((ext_vector_type(4)));
typedef float    f32x4 __attribute__((ext_vector_type(4)));

__device__ __forceinline__ uint32_t umin_(uint32_t a, uint32_t b) { return a < b ? a : b; }
__device__ __forceinline__ uint32_t umax_(uint32_t a, uint32_t b) { return a < b ? b : a; }

// ------------------------------------------------- X -> f16 + row sq-sums (+ zero out)
__global__ __launch_bounds__(256) void split_k(const float* __restrict__ X,
                                               _Float16* __restrict__ Xh,
                                               float* __restrict__ sqX,
                                               float* __restrict__ out) {
    if (blockIdx.x == 0 && threadIdx.x == 0) out[0] = 0.0f;  // finalize runs later on stream
    const int row  = blockIdx.x * 4 + (threadIdx.x >> 6);
    const int lane = threadIdx.x & 63;
    const float4 v = *(const float4*)&X[(size_t)row * DX + lane * 4];
    float s = v.x * v.x + v.y * v.y + v.z * v.z + v.w * v.w;
    f16x4 h;
    h[0] = (_Float16)v.x; h[1] = (_Float16)v.y;
    h[2] = (_Float16)v.z; h[3] = (_Float16)v.w;
    *(f16x4*)&Xh[(size_t)row * DX + lane * 4] = h;
    #pragma unroll
    for (int o = 32; o > 0; o >>= 1) s += __shfl_down(s, o);
    if (lane == 0) sqX[row] = s;
}

// ------------------------------------------------- f16 MFMA GEMM + fused packed top-5
// Double-buffered: DMA for chunk c+1 issued at top of chunk c; single barrier/chunk, so
// its vmcnt drain finds the transfer already complete (overlap instead of stall).
// CORRECTNESS/PERF NOTES (hard-won):
//  * __launch_bounds__(256,2), NOT (256,4): min-waves 4 clamps VGPR to 64 -> scratch spill
//    (R4: WRITE_SIZE 1 MB -> 1.07 GB).
//  * NO runtime subscripts into register arrays: forces array to scratch for kernel
//    lifetime (R5: WRITE_SIZE 711 MB). Constant-index select chains only.
__global__ __launch_bounds__(256, 2) void mfma_topk_k(const _Float16* __restrict__ Xh,
                                                      const float* __restrict__ sqX,
                                                      uint32_t* __restrict__ partials) {
    __shared__ __align__(16) uint8_t smem[2 * BUFB];   // ping-pong B staging
    __shared__ uint32_t mb2[RBLK][2][KNN];             // cross-wave merge (2.5 KB)

    const int tid  = threadIdx.x;
    const int w    = tid >> 6;
    const int lane = tid & 63;
    const int n    = lane & 15;
    const int quad = lane >> 4;
    const int x7   = n & 7;
    const int h    = w >> 1;
    const int sp   = w & 1;
    const int ib   = blockIdx.x * RBLK;
    const int jb0  = blockIdx.y * JS;
    const int rowbase = ib + h * 32;

    // A fragments: 2 rowgroups x 8 k-steps (A layout: row=lane&15, k=quad*8+j)
    f16x8 Ah[2][8];
    #pragma unroll
    for (int g = 0; g < 2; ++g)
        #pragma unroll
        for (int ks = 0; ks < 8; ++ks)
            Ah[g][ks] = *(const f16x8*)(Xh + (size_t)(rowbase + g * 16 + n) * DX + ks * 32 + quad * 8);

    float sqi[2][4];
    #pragma unroll
    for (int g = 0; g < 2; ++g) {
        const float4 t = *(const float4*)&sqX[rowbase + g * 16 + quad * 4];
        sqi[g][0] = t.x; sqi[g][1] = t.y; sqi[g][2] = t.z; sqi[g][3] = t.w;
    }

    uint32_t best[8][KNN];   // q = g*4+r; ascending; compile-time indices only
    #pragma unroll
    for (int q = 0; q < 8; ++q)
        #pragma unroll
        for (int k = 0; k < KNN; ++k) best[q][k] = 0xFFFFFFFFu;

    // DMA source offsets: inst t=w*4+u covers slots q=t*64+lane; row=q>>5, c=(q&31)^(row&7)
    int srcoff[4];
    #pragma unroll
    for (int u = 0; u < 4; ++u) {
        const int row = (w * 4 + u) * 2 + (lane >> 5);
        const int c   = (lane & 31) ^ (row & 7);
        srcoff[u] = row * DX + c * 8;
    }

    // B-read base decomposition: slot(ks) = bq + ((ks*4)^x4); even ks -> beven+ks*4,
    // odd ks -> bodd+(ks-1)*4 (base reg + immediate offset, zero per-read VALU)
    const int bq    = (sp * 16 + n) * 32 + (quad ^ (x7 & 3));
    const int x4    = x7 & 4;
    const int beven = bq + x4;
    const int bodd  = bq + 4 - x4;

    // prologue: stage chunk 0 into buffer 0
    {
        const _Float16* srcb = Xh + (size_t)jb0 * DX;
        #pragma unroll
        for (int u = 0; u < 4; ++u)
            __builtin_amdgcn_global_load_lds(
                (const __attribute__((address_space(1))) uint32_t*)(srcb + srcoff[u]),
                (__attribute__((address_space(3))) uint32_t*)(smem + (w * 4 + u) * 1024),
                16, 0, 0);
    }

    for (int jc = 0; jc < NCHUNK; ++jc) {
        __syncthreads();   // drains vmcnt: buf[jc&1] ready; prior readers of other buf done
        if (jc + 1 < NCHUNK) {
            const _Float16* srcb = Xh + (size_t)(jb0 + (jc + 1) * JT) * DX;
            uint8_t* db = smem + ((jc + 1) & 1) * BUFB;
            #pragma unroll
            for (int u = 0; u < 4; ++u)
                __builtin_amdgcn_global_load_lds(
                    (const __attribute__((address_space(1))) uint32_t*)(srcb + srcoff[u]),
                    (__attribute__((address_space(3))) uint32_t*)(db + (w * 4 + u) * 1024),
                    16, 0, 0);
        }
        const int j = jb0 + jc * JT + sp * 16 + n;   // this lane's column this chunk
        const float sqj = sqX[j];
        const f16x8* Bbuf = (const f16x8*)(smem + (jc & 1) * BUFB);

        f32x4 acc0, acc1;
        #pragma unroll
        for (int r = 0; r < 4; ++r) { acc0[r] = 0.0f; acc1[r] = 0.0f; }

        #pragma unroll
        for (int ks = 0; ks < 8; ++ks) {
            const int idx = (ks & 1) ? (bodd + (ks - 1) * 4) : (beven + ks * 4);
            const f16x8 b = Bbuf[idx];
            acc0 = __builtin_amdgcn_mfma_f32_16x16x32_f16(Ah[0][ks], b, acc0, 0, 0, 0);
            acc1 = __builtin_amdgcn_mfma_f32_16x16x32_f16(Ah[1][ks], b, acc1, 0, 0, 0);
        }

        // fold 8 candidates/lane (C layout: col=n, row=quad*4+reg)
        #pragma unroll
        for (int g = 0; g < 2; ++g) {
            #pragma unroll
            for (int r = 0; r < 4; ++r) {
                const int i = rowbase + g * 16 + quad * 4 + r;
                const float a = (g == 0) ? acc0[r] : acc1[r];
                const float d2 = fmaf(-2.0f, a, sqi[g][r] + sqj);
                uint32_t cand = (__float_as_uint(d2) & 0xFFFFE000u) | (uint32_t)j;
                cand = (j == i) ? 0xFFFFFFFFu : cand;   // reference drops the diagonal
                const int q = g * 4 + r;
                if (cand < best[q][KNN - 1]) {
                    uint32_t ck = cand;
                    #pragma unroll
                    for (int k = 0; k < KNN; ++k) {
                        const uint32_t bk = best[q][k];
                        best[q][k] = umin_(ck, bk); ck = umax_(ck, bk);
                    }
                }
            }
        }
    }

    // per-q: butterfly-merge sorted-5 across the 16 n-lanes, then immediate LDS dump
    #pragma unroll
    for (int q = 0; q < 8; ++q) {
        uint32_t a0 = best[q][0], a1 = best[q][1], a2 = best[q][2],
                 a3 = best[q][3], a4 = best[q][4];
        #pragma unroll
        for (int mask = 1; mask <= 8; mask <<= 1) {
            const uint32_t b0 = __shfl_xor(a0, mask);
            const uint32_t b1 = __shfl_xor(a1, mask);
            const uint32_t b2 = __shfl_xor(a2, mask);
            const uint32_t b3 = __shfl_xor(a3, mask);
            const uint32_t b4 = __shfl_xor(a4, mask);
            const uint32_t c0 = umin_(a0, b0);
            const uint32_t c1 = umin_(umin_(a1, b1), umax_(a0, b0));
            const uint32_t c2 = umin_(umin_(a2, b2), umin_(umax_(a0, b1), umax_(a1, b0)));
            const uint32_t c3 = umin_(umin_(a3, b3),
                                      umin_(umax_(a1, b1), umin_(umax_(a0, b2), umax_(a2, b0))));
            const uint32_t c4 = umin_(umin_(a4, b4),
                                      umin_(umin_(umax_(a0, b3), umax_(a1, b2)),
                                            umin_(umax_(a2, b1), umax_(a3, b0))));
            a0 = c0; a1 = c1; a2 = c2; a3 = c3; a4 = c4;
        }
        const int rloc = h * 32 + (q >> 2) * 16 + quad * 4 + (q & 3);
        uint32_t v = a0;                 // lane n gets element n via select chain
        v = (n == 1) ? a1 : v;
        v = (n == 2) ? a2 : v;
        v = (n == 3) ? a3 : v;
        v = (n == 4) ? a4 : v;
        if (n < KNN) mb2[rloc][sp][n] = v;
    }
    __syncthreads();

    // cross-wave (sp) merge; emit KEEP=8 per row per split
    if (tid < RBLK) {
        const uint32_t a0 = mb2[tid][0][0], a1 = mb2[tid][0][1], a2 = mb2[tid][0][2],
                       a3 = mb2[tid][0][3], a4 = mb2[tid][0][4];
        const uint32_t b0 = mb2[tid][1][0], b1 = mb2[tid][1][1], b2 = mb2[tid][1][2],
                       b3 = mb2[tid][1][3], b4 = mb2[tid][1][4];
        uint32_t o[KEEP];
        o[0] = umin_(a0, b0);
        o[1] = umin_(umin_(a1, b1), umax_(a0, b0));
        o[2] = umin_(umin_(a2, b2), umin_(umax_(a0, b1), umax_(a1, b0)));
        o[3] = umin_(umin_(a3, b3), umin_(umax_(a1, b1), umin_(umax_(a0, b2), umax_(a2, b0))));
        o[4] = umin_(umin_(a4, b4), umin_(umin_(umax_(a0, b3), umax_(a1, b2)),
                                          umin_(umax_(a2, b1), umax_(a3, b0))));
        o[5] = umin_(umin_(umax_(a0, b4), umax_(a4, b0)),
                     umin_(umax_(a1, b3), umin_(umax_(a2, b2), umax_(a3, b1))));
        o[6] = umin_(umin_(umax_(a1, b4), umax_(a4, b1)),
                     umin_(umax_(a2, b3), umax_(a3, b2)));
        o[7] = umin_(umax_(a2, b4), umin_(umax_(a3, b3), umax_(a4, b2)));
        #pragma unroll
        for (int k = 0; k < KEEP; ++k)
            partials[(size_t)(ib + tid) * NPOOL + blockIdx.y * KEEP + k] = o[k];
    }
}

// ------------------------------------------------- one wave per row: bitonic-64 approx
// sort, exact fp32 re-rank of top-16 (4 lanes/cand), bitonic-16 exact sort, lid, loss
__global__ __launch_bounds__(256) void finalize_k(const uint32_t* __restrict__ parts,
                                                  const float* __restrict__ X,
                                                  const float* __restrict__ Z,
                                                  const float* __restrict__ sqX,
                                                  float* __restrict__ out) {
    __shared__ float wsum[4];
    const int wv   = threadIdx.x >> 6;
    const int lane = threadIdx.x & 63;
    const int i    = blockIdx.x * 4 + wv;

    // bitonic sort the 64 packed candidates across lanes (keys distinct: disjoint j)
    uint32_t v = parts[(size_t)i * NPOOL + lane];
    #pragma unroll
    for (int kk = 2; kk <= 64; kk <<= 1) {
        #pragma unroll
        for (int jj = kk >> 1; jj > 0; jj >>= 1) {
            const uint32_t o = __shfl_xor(v, jj);
            const bool keepmin = ((lane & kk) == 0) == ((lane & jj) == 0);
            v = keepmin ? umin_(v, o) : umax_(v, o);
        }
    }
    // lanes 0..15 now hold the approx top-16 ascending

    // exact fp32 d2: candidate c = lane>>2, quarter qtr = lane&3 (64 dims each)
    const int c = lane >> 2, qtr = lane & 3;
    const int jc = (int)(__shfl(v, c) & 0x1FFFu);
    const float4* xi = (const float4*)(X + (size_t)i * DX) + qtr * 16;
    const float4* xj = (const float4*)(X + (size_t)jc * DX) + qtr * 16;
    float a0 = 0.f, a1 = 0.f, a2 = 0.f, a3 = 0.f;
    #pragma unroll
    for (int t = 0; t < 16; t += 4) {
        const float4 u0 = xi[t],     w0 = xj[t];
        const float4 u1 = xi[t + 1], w1 = xj[t + 1];
        const float4 u2 = xi[t + 2], w2 = xj[t + 2];
        const float4 u3 = xi[t + 3], w3 = xj[t + 3];
        a0 = fmaf(u0.x, w0.x, fmaf(u0.y, w0.y, fmaf(u0.z, w0.z, fmaf(u0.w, w0.w, a0))));
        a1 = fmaf(u1.x, w1.x, fmaf(u1.y, w1.y, fmaf(u1.z, w1.z, fmaf(u1.w, w1.w, a1))));
        a2 = fmaf(u2.x, w2.x, fmaf(u2.y, w2.y, fmaf(u2.z, w2.z, fmaf(u2.w, w2.w, a2))));
        a3 = fmaf(u3.x, w3.x, fmaf(u3.y, w3.y, fmaf(u3.z, w3.z, fmaf(u3.w, w3.w, a3))));
    }
    float dot = (a0 + a1) + (a2 + a3);
    dot += __shfl_xor(dot, 1);
    dot += __shfl_xor(dot, 2);
    const float d2x = (sqX[i] + sqX[jc]) - 2.0f * dot;
    const unsigned long long key =
        ((unsigned long long)__float_as_uint(d2x) << 32) | (unsigned)jc;

    // gather the 16 exact keys to lanes 0..15, bitonic-sort them (exact (d2, j) lex)
    unsigned long long k16 = __shfl(key, (lane * 4) & 63);
    if (lane >= 16) k16 = 0xFFFFFFFFFFFFFFFFull;
    #pragma unroll
    for (int kk = 2; kk <= 16; kk <<= 1) {
        #pragma unroll
        for (int jj = kk >> 1; jj > 0; jj >>= 1) {
            const unsigned long long o = __shfl_xor(k16, jj);
            const bool keepmin = ((lane & kk) == 0) == ((lane & jj) == 0);
            k16 = keepmin ? (k16 < o ? k16 : o) : (k16 < o ? o : k16);
        }
    }

    // lanes 0..4 hold the exact top-5 ascending
    const float d2k = __uint_as_float((uint32_t)(k16 >> 32));
    const int   jk  = (int)(k16 & 0x1FFFull);
    float lkx = 0.0f, lkz = 0.0f;
    if (lane < KNN) {
        lkx = log10f(sqrtf(fmaxf(d2k, 0.0f)) + EPS);
        const float4* zi = (const float4*)(Z + (size_t)i * DZ);
        const float4* zj = (const float4*)(Z + (size_t)jk * DZ);
        float s0 = 0.f, s1 = 0.f, s2 = 0.f, s3 = 0.f;
        #pragma unroll
        for (int t = 0; t < 16; t += 4) {
            const float4 u0 = zi[t],     w0 = zj[t];
            const float4 u1 = zi[t + 1], w1 = zj[t + 1];
            const float4 u2 = zi[t + 2], w2 = zj[t + 2];
            const float4 u3 = zi[t + 3], w3 = zj[t + 3];
            const float d0x = u0.x - w0.x, d0y = u0.y - w0.y, d0z = u0.z - w0.z, d0w = u0.w - w0.w;
            const float d1x = u1.x - w1.x, d1y = u1.y - w1.y, d1z = u1.z - w1.z, d1w = u1.w - w1.w;
            const float d2x_ = u2.x - w2.x, d2y = u2.y - w2.y, d2z_ = u2.z - w2.z, d2w = u2.w - w2.w;
            const float d3x = u3.x - w3.x, d3y = u3.y - w3.y, d3z = u3.z - w3.z, d3w = u3.w - w3.w;
            s0 = fmaf(d0x, d0x, fmaf(d0y, d0y, fmaf(d0z, d0z, fmaf(d0w, d0w, s0))));
            s1 = fmaf(d1x, d1x, fmaf(d1y, d1y, fmaf(d1z, d1z, fmaf(d1w, d1w, s1))));
            s2 = fmaf(d2x_, d2x_, fmaf(d2y, d2y, fmaf(d2z_, d2z_, fmaf(d2w, d2w, s2))));
            s3 = fmaf(d3x, d3x, fmaf(d3y, d3y, fmaf(d3z, d3z, fmaf(d3w, d3w, s3))));
        }
        const float d2z = (s0 + s1) + (s2 + s3);
        lkz = log10f(sqrtf(fmaxf(d2z, 0.0f)) + EPS);
    }
    const float l4x = __shfl(lkx, KNN - 1);
    const float l4z = __shfl(lkz, KNN - 1);
    float sx = lkx, sz = lkz;            // lanes 5..7 contribute 0
    sx += __shfl_xor(sx, 1); sz += __shfl_xor(sz, 1);
    sx += __shfl_xor(sx, 2); sz += __shfl_xor(sz, 2);
    sx += __shfl_xor(sx, 4); sz += __shfl_xor(sz, 4);

    if (lane == 0) {
        const float lx = -(sx - (float)KNN * l4x);
        const float lz = -(sz - (float)KNN * l4z);
        const float diff = lx - lz;
        wsum[wv] = diff * diff * (1.0f / ((float)NR * KNN * 10.0f));
    }
    __syncthreads();
    if (threadIdx.x == 0)
        atomicAdd(out, wsum[0] + wsum[1] + wsum[2] + wsum[3]);
}

// ---------------------------------------------------------------- launch
extern "C" void kernel_launch(void* const* d_in, const int* in_sizes, int n_in,
                              void* d_out, int out_size, void* d_ws, size_t ws_size,
                              hipStream_t stream) {
    const float* X = (const float*)d_in[0];
    const float* Z = (const float*)d_in[1];
    float* out = (float*)d_out;

    char* ws = (char*)d_ws;
    float*     sqX      = (float*)ws;                         // 32 KB
    uint32_t*  partials = (uint32_t*)(ws + 32768);            // 8192*64*4 = 2 MB
    _Float16*  Xh       = (_Float16*)(ws + 32768 + 2097152);  // 4 MB

    split_k<<<NR / 4, 256, 0, stream>>>(X, Xh, sqX, out);
    mfma_topk_k<<<dim3(NR / RBLK, NSPLIT), 256, 0, stream>>>(Xh, sqX, partials);
    finalize_k<<<NR / 4, 256, 0, stream>>>(partials, X, Z, sqX, out);
}

// Round 8
// 182.754 us; speedup vs baseline: 2.3823x; 1.0871x over previous
//
#include <hip/hip_runtime.h>
#include <math.h>
#include <stdint.h>

#define EPS     1e-7f
#define NR      8192
#define DX      256
#define DZ      64
#define KNN     5
#define KEEP    8               // per-split kept candidates (packed u32)
#define NSPLIT  8
#define NPOOL   (NSPLIT * KEEP) // 64 = one per lane in finalize
#define NCAND   16              // exact-recompute pool in finalize
#define JS      (NR / NSPLIT)   // 1024
#define JT      64              // j-cols staged per chunk
#define NCHUNK  (JS / JT)       // 16
#define RBLK    64              // i-rows per block

typedef _Float16 f16x8 __attribute__((ext_vector_type(8)));
typedef _Float16 f16x4 __attribute__((ext_vector_type(4)));
typedef float    f32x4 __attribute__((ext_vector_type(4)));

__device__ __forceinline__ uint32_t umin_(uint32_t a, uint32_t b) { return a < b ? a : b; }
__device__ __forceinline__ uint32_t umax_(uint32_t a, uint32_t b) { return a < b ? b : a; }

// ------------------------------------------------- X -> f16 + row sq-sums (+ zero out)
__global__ __launch_bounds__(256) void split_k(const float* __restrict__ X,
                                               _Float16* __restrict__ Xh,
                                               float* __restrict__ sqX,
                                               float* __restrict__ out) {
    if (blockIdx.x == 0 && threadIdx.x == 0) out[0] = 0.0f;  // finalize runs later on stream
    const int row  = blockIdx.x * 4 + (threadIdx.x >> 6);
    const int lane = threadIdx.x & 63;
    const float4 v = *(const float4*)&X[(size_t)row * DX + lane * 4];
    float s = v.x * v.x + v.y * v.y + v.z * v.z + v.w * v.w;
    f16x4 h;
    h[0] = (_Float16)v.x; h[1] = (_Float16)v.y;
    h[2] = (_Float16)v.z; h[3] = (_Float16)v.w;
    *(f16x4*)&Xh[(size_t)row * DX + lane * 4] = h;
    #pragma unroll
    for (int o = 32; o > 0; o >>= 1) s += __shfl_down(s, o);
    if (lane == 0) sqX[row] = s;
}

// ------------------------------------------------- f16 MFMA GEMM + fused packed top-5
// R6 structure verbatim (93.7 us): single-buffer JT=64, 16 chunks; explicit double-buffer
// regressed (R7: 100 us — doubled barrier count, implicit wave overlap already covers DMA).
// CORRECTNESS/PERF NOTES (hard-won):
//  * __launch_bounds__(256,2), NOT (256,4): min-waves 4 clamps VGPR to 64 -> scratch spill
//    (R4: WRITE_SIZE 1 MB -> 1.07 GB).
//  * NO runtime subscripts into register arrays: forces array to scratch for kernel
//    lifetime (R5: WRITE_SIZE 711 MB). Constant-index select chains only.
__global__ __launch_bounds__(256, 2) void mfma_topk_k(const _Float16* __restrict__ Xh,
                                                      const float* __restrict__ sqX,
                                                      uint32_t* __restrict__ partials) {
    __shared__ __align__(16) uint8_t smem[32768];      // B staging: 2048 slots x 16 B
    __shared__ uint32_t mb2[RBLK][2][KNN];             // cross-wave merge (2.5 KB)
    f16x8* BhV = (f16x8*)smem;

    const int tid  = threadIdx.x;
    const int w    = tid >> 6;
    const int lane = tid & 63;
    const int n    = lane & 15;
    const int quad = lane >> 4;
    const int x7   = n & 7;
    const int h    = w >> 1;
    const int sp   = w & 1;
    const int ib   = blockIdx.x * RBLK;
    const int jb0  = blockIdx.y * JS;
    const int rowbase = ib + h * 32;

    // A fragments: 2 rowgroups x 8 k-steps (A layout: row=lane&15, k=quad*8+j)
    f16x8 Ah[2][8];
    #pragma unroll
    for (int g = 0; g < 2; ++g)
        #pragma unroll
        for (int ks = 0; ks < 8; ++ks)
            Ah[g][ks] = *(const f16x8*)(Xh + (size_t)(rowbase + g * 16 + n) * DX + ks * 32 + quad * 8);

    float sqi[2][4];
    #pragma unroll
    for (int g = 0; g < 2; ++g) {
        const float4 t = *(const float4*)&sqX[rowbase + g * 16 + quad * 4];
        sqi[g][0] = t.x; sqi[g][1] = t.y; sqi[g][2] = t.z; sqi[g][3] = t.w;
    }

    uint32_t best[8][KNN];   // q = g*4+r; ascending; compile-time indices only
    #pragma unroll
    for (int q = 0; q < 8; ++q)
        #pragma unroll
        for (int k = 0; k < KNN; ++k) best[q][k] = 0xFFFFFFFFu;

    // staging source map: slot q = w*512 + u*64 + lane holds row sj=q>>5, chunk c=(q&31)^(sj&7)
    int srcoff[8];
    #pragma unroll
    for (int u = 0; u < 8; ++u) {
        const int q  = w * 512 + u * 64 + lane;
        const int sj = q >> 5;
        const int c  = (q & 31) ^ (sj & 7);
        srcoff[u] = sj * DX + c * 8;
    }

    for (int jc = 0; jc < NCHUNK; ++jc) {
        const int jb = jb0 + jc * JT;
        __syncthreads();  // previous chunk's readers done
        #pragma unroll
        for (int u = 0; u < 8; ++u) {
            const _Float16* src = Xh + (size_t)jb * DX + srcoff[u];
            uint8_t* dst = smem + (size_t)(w * 512 + u * 64) * 16;  // wave-uniform; HW adds lane*16
            __builtin_amdgcn_global_load_lds((const __attribute__((address_space(1))) uint32_t*)src,
                                             (__attribute__((address_space(3))) uint32_t*)dst,
                                             16, 0, 0);
        }
        __syncthreads();  // drains vmcnt -> staging visible

        f32x4 acc[2][2];  // [si][g]
        #pragma unroll
        for (int si = 0; si < 2; ++si)
            #pragma unroll
            for (int g = 0; g < 2; ++g)
                #pragma unroll
                for (int r = 0; r < 4; ++r) acc[si][g][r] = 0.0f;

        #pragma unroll
        for (int ks = 0; ks < 8; ++ks) {
            #pragma unroll
            for (int si = 0; si < 2; ++si) {
                const int s   = sp * 2 + si;
                const int idx = (s * 16 + n) * 32 + ((ks * 4 + quad) ^ x7);
                const f16x8 b = BhV[idx];
                acc[si][0] = __builtin_amdgcn_mfma_f32_16x16x32_f16(Ah[0][ks], b, acc[si][0], 0, 0, 0);
                acc[si][1] = __builtin_amdgcn_mfma_f32_16x16x32_f16(Ah[1][ks], b, acc[si][1], 0, 0, 0);
            }
        }

        // fold 16 candidates/lane (C layout: col=n, row=quad*4+reg)
        #pragma unroll
        for (int si = 0; si < 2; ++si) {
            const int j = jb + (sp * 2 + si) * 16 + n;
            const float sqj = sqX[j];
            #pragma unroll
            for (int g = 0; g < 2; ++g) {
                #pragma unroll
                for (int r = 0; r < 4; ++r) {
                    const int i = rowbase + g * 16 + quad * 4 + r;
                    if (j == i) continue;  // reference drops the diagonal
                    const float d2 = (sqi[g][r] + sqj) - 2.0f * acc[si][g][r];
                    const uint32_t cand = (__float_as_uint(d2) & 0xFFFFE000u) | (uint32_t)j;
                    const int q = g * 4 + r;
                    if (cand < best[q][KNN - 1]) {
                        uint32_t ck = cand;
                        #pragma unroll
                        for (int k = 0; k < KNN; ++k) {
                            const uint32_t bk = best[q][k];
                            best[q][k] = umin_(ck, bk); ck = umax_(ck, bk);
                        }
                    }
                }
            }
        }
    }

    // per-q: butterfly-merge sorted-5 across the 16 n-lanes, then immediate LDS dump
    #pragma unroll
    for (int q = 0; q < 8; ++q) {
        uint32_t a0 = best[q][0], a1 = best[q][1], a2 = best[q][2],
                 a3 = best[q][3], a4 = best[q][4];
        #pragma unroll
        for (int mask = 1; mask <= 8; mask <<= 1) {
            const uint32_t b0 = __shfl_xor(a0, mask);
            const uint32_t b1 = __shfl_xor(a1, mask);
            const uint32_t b2 = __shfl_xor(a2, mask);
            const uint32_t b3 = __shfl_xor(a3, mask);
            const uint32_t b4 = __shfl_xor(a4, mask);
            const uint32_t c0 = umin_(a0, b0);
            const uint32_t c1 = umin_(umin_(a1, b1), umax_(a0, b0));
            const uint32_t c2 = umin_(umin_(a2, b2), umin_(umax_(a0, b1), umax_(a1, b0)));
            const uint32_t c3 = umin_(umin_(a3, b3),
                                      umin_(umax_(a1, b1), umin_(umax_(a0, b2), umax_(a2, b0))));
            const uint32_t c4 = umin_(umin_(a4, b4),
                                      umin_(umin_(umax_(a0, b3), umax_(a1, b2)),
                                            umin_(umax_(a2, b1), umax_(a3, b0))));
            a0 = c0; a1 = c1; a2 = c2; a3 = c3; a4 = c4;
        }
        const int rloc = h * 32 + (q >> 2) * 16 + quad * 4 + (q & 3);
        uint32_t v = a0;                 // lane n gets element n via select chain
        v = (n == 1) ? a1 : v;
        v = (n == 2) ? a2 : v;
        v = (n == 3) ? a3 : v;
        v = (n == 4) ? a4 : v;
        if (n < KNN) mb2[rloc][sp][n] = v;
    }
    __syncthreads();

    // cross-wave (sp) merge; emit KEEP=8 per row per split
    if (tid < RBLK) {
        const uint32_t a0 = mb2[tid][0][0], a1 = mb2[tid][0][1], a2 = mb2[tid][0][2],
                       a3 = mb2[tid][0][3], a4 = mb2[tid][0][4];
        const uint32_t b0 = mb2[tid][1][0], b1 = mb2[tid][1][1], b2 = mb2[tid][1][2],
                       b3 = mb2[tid][1][3], b4 = mb2[tid][1][4];
        uint32_t o[KEEP];
        o[0] = umin_(a0, b0);
        o[1] = umin_(umin_(a1, b1), umax_(a0, b0));
        o[2] = umin_(umin_(a2, b2), umin_(umax_(a0, b1), umax_(a1, b0)));
        o[3] = umin_(umin_(a3, b3), umin_(umax_(a1, b1), umin_(umax_(a0, b2), umax_(a2, b0))));
        o[4] = umin_(umin_(a4, b4), umin_(umin_(umax_(a0, b3), umax_(a1, b2)),
                                          umin_(umax_(a2, b1), umax_(a3, b0))));
        o[5] = umin_(umin_(umax_(a0, b4), umax_(a4, b0)),
                     umin_(umax_(a1, b3), umin_(umax_(a2, b2), umax_(a3, b1))));
        o[6] = umin_(umin_(umax_(a1, b4), umax_(a4, b1)),
                     umin_(umax_(a2, b3), umax_(a3, b2)));
        o[7] = umin_(umax_(a2, b4), umin_(umax_(a3, b3), umax_(a4, b2)));
        #pragma unroll
        for (int k = 0; k < KEEP; ++k)
            partials[(size_t)(ib + tid) * NPOOL + blockIdx.y * KEEP + k] = o[k];
    }
}

// ------------------------------------------------- one wave per row, ROW-COALESCED re-rank:
// bitonic-64 approx sort; per candidate, ALL 64 lanes read its X row (1 KB coalesced, no
// 16B-scatter line amplification — that scatter was ~90 us in R3..R7); butterfly-reduced
// exact fp32 dots; bitonic-16 exact (d2,j) sort; lid; loss.
__global__ __launch_bounds__(256) void finalize_k(const uint32_t* __restrict__ parts,
                                                  const float* __restrict__ X,
                                                  const float* __restrict__ Z,
                                                  const float* __restrict__ sqX,
                                                  float* __restrict__ out) {
    __shared__ float wsum[4];
    const int wv   = threadIdx.x >> 6;
    const int lane = threadIdx.x & 63;
    const int i    = blockIdx.x * 4 + wv;

    // bitonic sort the 64 packed candidates across lanes (keys distinct: disjoint j)
    uint32_t v = parts[(size_t)i * NPOOL + lane];
    #pragma unroll
    for (int kk = 2; kk <= 64; kk <<= 1) {
        #pragma unroll
        for (int jj = kk >> 1; jj > 0; jj >>= 1) {
            const uint32_t o = __shfl_xor(v, jj);
            const bool keepmin = ((lane & kk) == 0) == ((lane & jj) == 0);
            v = keepmin ? umin_(v, o) : umax_(v, o);
        }
    }
    // lanes 0..15 hold the approx top-16 ascending

    // own-row fragment: 4 dims/lane (coalesced)
    const float4 xi = *(const float4*)(X + (size_t)i * DX + lane * 4);

    // exact fp32 dots: candidate c's j broadcast (readlane -> SGPR base), whole row
    // read coalesced by the full wave; per-lane 4-dim partial
    float p[16];
    #pragma unroll
    for (int c = 0; c < NCAND; ++c) {
        const int jc = (int)(__shfl(v, c) & 0x1FFFu);
        const float4 xj = *(const float4*)(X + (size_t)jc * DX + lane * 4);
        p[c] = fmaf(xi.x, xj.x, fmaf(xi.y, xj.y, fmaf(xi.z, xj.z, xi.w * xj.w)));
    }
    // reduce: 4 stages per candidate (16-lane block sums), constant-index select, 2 stages
    #pragma unroll
    for (int c = 0; c < NCAND; ++c) {
        p[c] += __shfl_xor(p[c], 1);
        p[c] += __shfl_xor(p[c], 2);
        p[c] += __shfl_xor(p[c], 4);
        p[c] += __shfl_xor(p[c], 8);
    }
    const int cs = lane & 15;
    float dotv = p[0];
    dotv = (cs == 1)  ? p[1]  : dotv;
    dotv = (cs == 2)  ? p[2]  : dotv;
    dotv = (cs == 3)  ? p[3]  : dotv;
    dotv = (cs == 4)  ? p[4]  : dotv;
    dotv = (cs == 5)  ? p[5]  : dotv;
    dotv = (cs == 6)  ? p[6]  : dotv;
    dotv = (cs == 7)  ? p[7]  : dotv;
    dotv = (cs == 8)  ? p[8]  : dotv;
    dotv = (cs == 9)  ? p[9]  : dotv;
    dotv = (cs == 10) ? p[10] : dotv;
    dotv = (cs == 11) ? p[11] : dotv;
    dotv = (cs == 12) ? p[12] : dotv;
    dotv = (cs == 13) ? p[13] : dotv;
    dotv = (cs == 14) ? p[14] : dotv;
    dotv = (cs == 15) ? p[15] : dotv;
    dotv += __shfl_xor(dotv, 16);
    dotv += __shfl_xor(dotv, 32);
    // every lane: full dot for candidate (lane&15); lane<16's own v gives matching j

    unsigned long long k16 = 0xFFFFFFFFFFFFFFFFull;
    const int jl = (int)(v & 0x1FFFu);
    if (lane < NCAND) {
        const float d2x = (sqX[i] + sqX[jl]) - 2.0f * dotv;
        k16 = ((unsigned long long)__float_as_uint(d2x) << 32) | (unsigned)jl;
    }
    // bitonic-16 on exact (d2, j) keys over lanes 0..15
    #pragma unroll
    for (int kk = 2; kk <= 16; kk <<= 1) {
        #pragma unroll
        for (int jj = kk >> 1; jj > 0; jj >>= 1) {
            const unsigned long long o = __shfl_xor(k16, jj);
            const bool keepmin = ((lane & kk) == 0) == ((lane & jj) == 0);
            k16 = keepmin ? (k16 < o ? k16 : o) : (k16 < o ? o : k16);
        }
    }

    // lanes 0..4 hold the exact top-5 ascending
    const float d2k = __uint_as_float((uint32_t)(k16 >> 32));
    const int   jk  = (int)(k16 & 0x1FFFull);
    float lkx = 0.0f;
    if (lane < KNN) lkx = log10f(sqrtf(fmaxf(d2k, 0.0f)) + EPS);
    const float l4x = __shfl(lkx, KNN - 1);
    float sx = lkx;                      // lanes 5..7 contribute 0
    sx += __shfl_xor(sx, 1);
    sx += __shfl_xor(sx, 2);
    sx += __shfl_xor(sx, 4);

    // z-distances, coalesced: 1 dim/lane; 5 neighbor rows read by the whole wave
    const float zi = Z[(size_t)i * DZ + lane];
    float zsum = 0.0f, l4z = 0.0f;
    #pragma unroll
    for (int k = 0; k < KNN; ++k) {
        const int jz = __shfl(jk, k);
        const float zj = Z[(size_t)jz * DZ + lane];
        const float d = zi - zj;
        float s = d * d;
        s += __shfl_xor(s, 1);
        s += __shfl_xor(s, 2);
        s += __shfl_xor(s, 4);
        s += __shfl_xor(s, 8);
        s += __shfl_xor(s, 16);
        s += __shfl_xor(s, 32);
        const float lk = log10f(sqrtf(fmaxf(s, 0.0f)) + EPS);
        zsum += lk;
        if (k == KNN - 1) l4z = lk;     // compile-time branch (unrolled)
    }

    if (lane == 0) {
        const float lx = -(__shfl(sx, 0) - (float)KNN * l4x);
        const float lz = -(zsum - (float)KNN * l4z);
        const float diff = lx - lz;
        wsum[wv] = diff * diff * (1.0f / ((float)NR * KNN * 10.0f));
    }
    __syncthreads();
    if (threadIdx.x == 0)
        atomicAdd(out, wsum[0] + wsum[1] + wsum[2] + wsum[3]);
}

// ---------------------------------------------------------------- launch
extern "C" void kernel_launch(void* const* d_in, const int* in_sizes, int n_in,
                              void* d_out, int out_size, void* d_ws, size_t ws_size,
                              hipStream_t stream) {
    const float* X = (const float*)d_in[0];
    const float* Z = (const float*)d_in[1];
    float* out = (float*)d_out;

    char* ws = (char*)d_ws;
    float*     sqX      = (float*)ws;                         // 32 KB
    uint32_t*  partials = (uint32_t*)(ws + 32768);            // 8192*64*4 = 2 MB
    _Float16*  Xh       = (_Float16*)(ws + 32768 + 2097152);  // 4 MB

    split_k<<<NR / 4, 256, 0, stream>>>(X, Xh, sqX, out);
    mfma_topk_k<<<dim3(NR / RBLK, NSPLIT), 256, 0, stream>>>(Xh, sqX, partials);
    finalize_k<<<NR / 4, 256, 0, stream>>>(partials, X, Z, sqX, out);
}